// Round 8
// baseline (67.455 us; speedup 1.0000x reference)
//
#include <hip/hip_runtime.h>
#include <math.h>

#ifndef M_PI
#define M_PI 3.14159265358979323846
#endif

#define NSIDE  128
#define NTHETA 511
#define MMAX   257
#define NPIX   196608
#define PCT_M  ((size_t)NTHETA * NTHETA)
#define MN     ((size_t)NTHETA * MMAX)   // one [k][m] plane
#define NCH    4                         // l-chunks per m (partials)
#define GROWS  8                         // rows per staged LDS group
#define NGRP   16                        // groups per chunk (128 rows)

// ftm partial kernel. Block -> (m, j) via pair-balancing: q pairs m=q with
// m=256-q (cnt(q)+cnt(256-q) ~ const), so consecutive-bid CU stripes get
// equal bytes. Each block: rows [j*128, +128) of slab m, ALL valid k columns
// [klo, 511-klo). Per row: one aligned dwordx2 sweep (256 thr * 8 B = 512
// floats >= cnt+1) staged to LDS, consumed thread-per-column. Double
// buffered; loads issued before consume (T14).
__global__ __launch_bounds__(256, 4)
void ftm_kernel(const float* __restrict__ x_re,
                const float* __restrict__ x_im,
                const float* __restrict__ pct,
                float* __restrict__ ftm_p)   // [NCH][2][k][m]
{
    const int q    = blockIdx.x >> 3;        // 0..128
    const int r    = blockIdx.x & 7;
    const int pick = r & 1;
    if (q == 128 && pick) return;            // m=128 covered once
    const int m = pick ? 256 - q : q;
    const int j = r >> 1;                    // 0..3

    const int klo   = (m >= 2) ? ((m + 1) >> 1) - 1 : 0;
    const int cnt   = NTHETA - 2 * klo;      // odd, 257..511
    const int l0    = j * 128;
    const int nrows = min(128, NTHETA - l0); // 128 or 127
    const int nT    = (cnt + 2) >> 1;        // dwordx2 loads per row

    __shared__ float2 xs[128];
    __shared__ float  tile[2][GROWS][512];

    const int tid = threadIdx.x;
    if (tid < nrows) {
        int l = l0 + tid;
        xs[tid] = make_float2(x_re[(size_t)l * MMAX + m],
                              x_im[(size_t)l * MMAX + m]);
    }

    const int par = (m + klo + l0) & 1;      // absolute float-index parity of row 0
    const bool loader = (tid < nT);

    float a0r = 0.f, a0i = 0.f, a1r = 0.f, a1i = 0.f;
    float2 st[GROWS];

    #define LOADG(g)                                                         \
        _Pragma("unroll")                                                    \
        for (int rr = 0; rr < GROWS; ++rr) {                                 \
            int row = (g) * GROWS + rr;                                      \
            bool ok = (row < nrows) && loader;                               \
            size_t A  = (size_t)m * PCT_M +                                  \
                        (size_t)(l0 + (ok ? row : 0)) * NTHETA + klo;        \
            size_t A8 = A & ~(size_t)1;                                      \
            st[rr] = ok ? *(const float2*)(pct + A8 + 2 * tid)               \
                        : make_float2(0.f, 0.f);                             \
        }

    #define WRITEG(g, buf)                                                   \
        _Pragma("unroll")                                                    \
        for (int rr = 0; rr < GROWS; ++rr) {                                 \
            int row = (g) * GROWS + rr;                                      \
            if (row < nrows && loader)                                       \
                *(float2*)&tile[buf][rr][2 * tid] = st[rr];                  \
        }

    #define CONSUMEG(g, buf)                                                 \
        _Pragma("unroll")                                                    \
        for (int rr = 0; rr < GROWS; ++rr) {                                 \
            int row = (g) * GROWS + rr;                                      \
            if (row < nrows) {                                               \
                int s2 = (par + row) & 1;                                    \
                float2 xv = xs[row];                                         \
                float v0 = tile[buf][rr][tid + s2];                          \
                int i1 = (tid + 256 < cnt) ? (tid + 256 + s2) : s2;          \
                float v1 = tile[buf][rr][i1];                                \
                a0r = fmaf(xv.x, v0, a0r);  a0i = fmaf(xv.y, v0, a0i);       \
                a1r = fmaf(xv.x, v1, a1r);  a1i = fmaf(xv.y, v1, a1i);       \
            }                                                                \
        }

    LOADG(0);
    WRITEG(0, 0);
    __syncthreads();
    int buf = 0;
    for (int g = 0; g < NGRP; ++g) {
        if (g + 1 < NGRP) { LOADG(g + 1); }
        CONSUMEG(g, buf);
        if (g + 1 < NGRP) {
            WRITEG(g + 1, buf ^ 1);
            __syncthreads();
        }
        buf ^= 1;
    }

    float* base = ftm_p + (size_t)j * 2 * MN;
    const int k0 = klo + tid;
    if (tid < cnt) {
        base[(size_t)k0 * MMAX + m]      = a0r;
        base[MN + (size_t)k0 * MMAX + m] = a0i;
    }
    if (tid + 256 < cnt) {
        const int k1 = k0 + 256;
        base[(size_t)k1 * MMAX + m]      = a1r;
        base[MN + (size_t)k1 * MMAX + m] = a1i;
    }
    #undef LOADG
    #undef WRITEG
    #undef CONSUMEG
}

// ring kernel: direct inverse rFFT per ring at pixel azimuths; sums the
// NCH l-partials while staging into LDS (combine folded in).
__global__ __launch_bounds__(256)
void ring_kernel(const float* __restrict__ ftm_p, float* __restrict__ out)
{
    const int t = blockIdx.y;
    int nphi, cum;
    double phi0;
    if (t < NSIDE - 1) {                       // north polar cap
        nphi = 4 * (t + 1);
        cum  = 2 * t * (t + 1);
        phi0 = M_PI / (4.0 * (t + 1));
    } else if (t <= 3 * NSIDE - 1) {           // equatorial belt
        nphi = 4 * NSIDE;
        cum  = 2 * (NSIDE - 1) * NSIDE + (t - (NSIDE - 1)) * 4 * NSIDE;
        phi0 = (M_PI / (2.0 * NSIDE)) * (0.5 * (double)((t - NSIDE + 2) % 2));
    } else {                                   // south polar cap
        int s = 4 * NSIDE - 1 - t;
        nphi = 4 * s;
        cum  = NPIX - 2 * s * (s + 1);
        phi0 = M_PI / (4.0 * s);
    }
    if ((int)blockIdx.x * 256 >= nphi) return;

    const int mtop = nphi / 2;                 // <= 256
    __shared__ float fr[MMAX];
    __shared__ float fi[MMAX];
    for (int i = threadIdx.x; i <= mtop; i += 256) {
        size_t o = (size_t)t * MMAX + i;
        float sr = 0.f, si = 0.f;
        #pragma unroll
        for (int p = 0; p < NCH; ++p) {
            sr += ftm_p[(size_t)p * 2 * MN + o];
            si += ftm_p[(size_t)p * 2 * MN + MN + o];
        }
        fr[i] = sr;  fi[i] = si;
    }
    __syncthreads();

    const int k = blockIdx.x * 256 + threadIdx.x;
    if (k >= nphi) return;

    double phi = phi0 + (2.0 * M_PI) * ((double)k / (double)nphi);
    float sp, cp;
    sincosf((float)phi, &sp, &cp);

    float cr = 1.f, ci = 0.f;
    float acc = fr[0];
    for (int mm = 1; mm < mtop; ++mm) {
        float nr = cr * cp - ci * sp;
        float ni = cr * sp + ci * cp;
        cr = nr; ci = ni;
        acc += 2.f * (fr[mm] * cr - fi[mm] * ci);
    }
    {
        float nr = cr * cp - ci * sp;
        float ni = cr * sp + ci * cp;
        acc += fr[mtop] * nr - fi[mtop] * ni;
    }
    out[cum + k] = acc;
}

extern "C" void kernel_launch(void* const* d_in, const int* in_sizes, int n_in,
                              void* d_out, int out_size, void* d_ws, size_t ws_size,
                              hipStream_t stream)
{
    const float* x_re = (const float*)d_in[0];
    const float* x_im = (const float*)d_in[1];
    const float* pct  = (const float*)d_in[2];
    float* out = (float*)d_out;

    float* ftm_p = (float*)d_ws;   // [NCH][2][NTHETA][MMAX] = 4.2 MB

    ftm_kernel<<<dim3(129 * 8), 256, 0, stream>>>(x_re, x_im, pct, ftm_p);
    ring_kernel<<<dim3(2, NTHETA), 256, 0, stream>>>(ftm_p, out);
}

// Round 9
// 67.435 us; speedup vs baseline: 1.0003x; 1.0003x over previous
//
#include <hip/hip_runtime.h>
#include <math.h>

#ifndef M_PI
#define M_PI 3.14159265358979323846
#endif

#define NSIDE  128
#define NTHETA 511
#define MMAX   257
#define NPIX   196608
#define PCT_M  ((size_t)NTHETA * NTHETA)
#define MN     ((size_t)MMAX * NTHETA)   // one [m][k] plane (131327)
#define NCH    8                         // l-chunks (64 rows each, last=63)

// ftm partial kernel. Block = (q, lc): q pairs m=q with m=256-q (constant
// total bytes per block -> balanced), lc = 64-row l-chunk. Thread owns cols
// klo+tid and klo+tid+256 of WHOLE rows -> zero internal k-boundary
// over-fetch. Inner loop = R6's proven batched scalar-strided form.
__global__ __launch_bounds__(256)
void ftm_kernel(const float* __restrict__ x_re,
                const float* __restrict__ x_im,
                const float* __restrict__ pct,
                float* __restrict__ ftm_p)   // [lc][reim][m][k]
{
    const int q   = blockIdx.x >> 3;     // 0..128
    const int lc  = blockIdx.x & 7;      // 0..7
    const int l0  = lc * 64;
    const int tid = threadIdx.x;
    const int nr  = min(64, NTHETA - l0);    // 64, or 63 for lc=7

    __shared__ float2 xs[2][64];
    if (tid < 128) {
        const int side = tid >> 6, rr = tid & 63;
        const int m = side ? 256 - q : q;
        const int l = l0 + rr;
        float2 v = make_float2(0.f, 0.f);
        if (l < NTHETA)
            v = make_float2(x_re[(size_t)l * MMAX + m],
                            x_im[(size_t)l * MMAX + m]);
        xs[side][rr] = v;                    // zero-pad row 63 of last chunk
    }
    __syncthreads();

    for (int side = 0; side < 2; ++side) {
        if (side && q == 128) break;         // m=128 covered once
        const int m   = side ? 256 - q : q;
        const int klo = (m >= 2) ? ((m + 1) >> 1) - 1 : 0;
        const int cnt = NTHETA - 2 * klo;    // 257..511 (odd) -> col0 always valid
        const int k0  = klo + tid;
        const bool has2 = (tid + 256) < cnt;
        const int k1  = k0 + 256;

        const float* p = pct + (size_t)m * PCT_M + (size_t)l0 * NTHETA;
        float a0r = 0.f, a0i = 0.f, a1r = 0.f, a1i = 0.f;

        for (int b = 0; b < 8; ++b) {        // 8 batches x 8 rows
            float v0[8], v1[8];
            #pragma unroll
            for (int u = 0; u < 8; ++u) {
                int rr = b * 8 + u;
                int rc = rr < nr ? rr : nr - 1;   // clamped dup row (x=0)
                v0[u] = p[(size_t)rc * NTHETA + k0];
                v1[u] = has2 ? p[(size_t)rc * NTHETA + k1] : 0.f;
            }
            #pragma unroll
            for (int u = 0; u < 8; ++u) {
                float2 xv = xs[side][b * 8 + u];
                a0r = fmaf(xv.x, v0[u], a0r);  a0i = fmaf(xv.y, v0[u], a0i);
                a1r = fmaf(xv.x, v1[u], a1r);  a1i = fmaf(xv.y, v1[u], a1i);
            }
        }

        float* P = ftm_p + (size_t)lc * 2 * MN;      // [reim][m][k]
        P[(size_t)m * NTHETA + k0]      = a0r;       // coalesced (k contiguous)
        P[MN + (size_t)m * NTHETA + k0] = a0i;
        if (has2) {
            P[(size_t)m * NTHETA + k1]      = a1r;
            P[MN + (size_t)m * NTHETA + k1] = a1i;
        }
    }
}

// ring kernel: direct inverse rFFT per ring at pixel azimuths; sums the
// NCH l-partials during LDS staging (combine folded in, reads L3-resident).
__global__ __launch_bounds__(256)
void ring_kernel(const float* __restrict__ ftm_p, float* __restrict__ out)
{
    const int t = blockIdx.y;
    int nphi, cum;
    double phi0;
    if (t < NSIDE - 1) {                       // north polar cap
        nphi = 4 * (t + 1);
        cum  = 2 * t * (t + 1);
        phi0 = M_PI / (4.0 * (t + 1));
    } else if (t <= 3 * NSIDE - 1) {           // equatorial belt
        nphi = 4 * NSIDE;
        cum  = 2 * (NSIDE - 1) * NSIDE + (t - (NSIDE - 1)) * 4 * NSIDE;
        phi0 = (M_PI / (2.0 * NSIDE)) * (0.5 * (double)((t - NSIDE + 2) % 2));
    } else {                                   // south polar cap
        int s = 4 * NSIDE - 1 - t;
        nphi = 4 * s;
        cum  = NPIX - 2 * s * (s + 1);
        phi0 = M_PI / (4.0 * s);
    }
    if ((int)blockIdx.x * 256 >= nphi) return;

    const int mtop = nphi / 2;                 // <= 256
    __shared__ float fr[MMAX];
    __shared__ float fi[MMAX];
    for (int i = threadIdx.x; i <= mtop; i += 256) {
        const size_t o = (size_t)i * NTHETA + t;
        float sr = 0.f, si = 0.f;
        #pragma unroll
        for (int p = 0; p < NCH; ++p) {
            sr += ftm_p[(size_t)p * 2 * MN + o];
            si += ftm_p[(size_t)p * 2 * MN + MN + o];
        }
        fr[i] = sr;  fi[i] = si;
    }
    __syncthreads();

    const int k = blockIdx.x * 256 + threadIdx.x;
    if (k >= nphi) return;

    double phi = phi0 + (2.0 * M_PI) * ((double)k / (double)nphi);
    float sp, cp;
    sincosf((float)phi, &sp, &cp);

    float cr = 1.f, ci = 0.f;
    float acc = fr[0];
    for (int mm = 1; mm < mtop; ++mm) {
        float nr = cr * cp - ci * sp;
        float ni = cr * sp + ci * cp;
        cr = nr; ci = ni;
        acc += 2.f * (fr[mm] * cr - fi[mm] * ci);
    }
    {
        float nr = cr * cp - ci * sp;
        float ni = cr * sp + ci * cp;
        acc += fr[mtop] * nr - fi[mtop] * ni;
    }
    out[cum + k] = acc;
}

extern "C" void kernel_launch(void* const* d_in, const int* in_sizes, int n_in,
                              void* d_out, int out_size, void* d_ws, size_t ws_size,
                              hipStream_t stream)
{
    const float* x_re = (const float*)d_in[0];
    const float* x_im = (const float*)d_in[1];
    const float* pct  = (const float*)d_in[2];
    float* out = (float*)d_out;

    float* ftm_p = (float*)d_ws;   // [NCH][2][MMAX][NTHETA] = 8.4 MB

    ftm_kernel<<<dim3(129 * NCH), 256, 0, stream>>>(x_re, x_im, pct, ftm_p);
    ring_kernel<<<dim3(2, NTHETA), 256, 0, stream>>>(ftm_p, out);
}